// Round 3
// baseline (656.122 us; speedup 1.0000x reference)
//
#include <hip/hip_runtime.h>

// SelfAttention: B=4, T=4096, D=4096, H=128. Inputs fp32, output fp32
// (reference dtypes); internal compute bf16 MFMA (threshold is bf16-scale).
// Pipeline: tr_w (fp32 W -> bf16 Wt[384][4096]) -> qkv_proj (fp32 x @ Wt -> bf16 Q,K,V)
//           -> tr_v (V -> Vt[B][128][T]) -> flash (online softmax, fp32 out).

typedef __bf16 bf16_t;
typedef bf16_t bf16x8 __attribute__((ext_vector_type(8)));
typedef float f32x4 __attribute__((ext_vector_type(4)));
typedef float f32x8 __attribute__((ext_vector_type(8)));

#define MFMA16(A, B, C) __builtin_amdgcn_mfma_f32_16x16x32_bf16((A), (B), (C), 0, 0, 0)

__device__ __forceinline__ void async_cp16(const bf16_t* g, bf16_t* lds) {
  // 16B direct global->LDS. LDS dest = wave-uniform base + lane*16.
  __builtin_amdgcn_global_load_lds(
      (__attribute__((address_space(1))) unsigned int*)g,
      (__attribute__((address_space(3))) unsigned int*)lds, 16, 0, 0);
}

// ---------------- transpose W: 3x fp32 (4096,128) -> bf16 Wt (384,4096) -------
__global__ void tr_w(const float* __restrict__ w0, const float* __restrict__ w1,
                     const float* __restrict__ w2, bf16_t* __restrict__ wt) {
  __shared__ float tile[32][33];
  const int z = blockIdx.z;
  const float* src = (z == 0) ? w0 : (z == 1) ? w1 : w2;
  bf16_t* dst = wt + (size_t)z * 128 * 4096;
  const int c0 = blockIdx.x * 32;  // col (H) base
  const int r0 = blockIdx.y * 32;  // row (D) base
  const int tx = threadIdx.x, ty = threadIdx.y;
#pragma unroll
  for (int j = 0; j < 4; ++j)
    tile[ty + 8 * j][tx] = src[(size_t)(r0 + ty + 8 * j) * 128 + c0 + tx];
  __syncthreads();
#pragma unroll
  for (int j = 0; j < 4; ++j)
    dst[(size_t)(c0 + ty + 8 * j) * 4096 + r0 + tx] = (bf16_t)tile[tx][ty + 8 * j];
}

// ---------------- transpose V: bf16 (B,4096,128) -> bf16 Vt (B,128,4096) ------
__global__ void tr_v(const bf16_t* __restrict__ v, bf16_t* __restrict__ vt) {
  __shared__ bf16_t tile[32][33];
  const int b = blockIdx.z;
  const bf16_t* src = v + (size_t)b * 4096 * 128;
  bf16_t* dst = vt + (size_t)b * 128 * 4096;
  const int c0 = blockIdx.x * 32;
  const int r0 = blockIdx.y * 32;
  const int tx = threadIdx.x, ty = threadIdx.y;
#pragma unroll
  for (int j = 0; j < 4; ++j)
    tile[ty + 8 * j][tx] = src[(size_t)(r0 + ty + 8 * j) * 128 + c0 + tx];
  __syncthreads();
#pragma unroll
  for (int j = 0; j < 4; ++j)
    dst[(size_t)(c0 + ty + 8 * j) * 4096 + r0 + tx] = tile[tx][ty + 8 * j];
}

// ---------------- fused QKV projection: fp32 (16384,4096) @ Wt -> 3x bf16 (16384,128)
// Block: 64 rows x 384 cols, BK=64. 4 waves; wave w -> cols [w*96, w*96+96).
// A tile: fp32 register loads -> cvt -> ds_write_b128 (bf16).
// B tile: bf16 global_load_lds width-16 staging.
__launch_bounds__(256, 1)
__global__ void qkv_proj(const float* __restrict__ x, const bf16_t* __restrict__ wt,
                         bf16_t* __restrict__ q, bf16_t* __restrict__ k,
                         bf16_t* __restrict__ v) {
  __shared__ __align__(16) bf16_t sA[64 * 64];    // [m][k], 8x16B chunks per row
  __shared__ __align__(16) bf16_t sB[384 * 64];   // [n][k], 8x16B chunks per row
  const int tid = threadIdx.x;
  const int w = tid >> 6, lane = tid & 63, lq = lane & 15, quad = lane >> 4;
  const int m0 = blockIdx.x * 64;

  // A staging role: thread t -> row t>>2, k-segment (t&3)*16 (16 fp32 = 4 float4)
  const int arow = tid >> 2, kseg = (tid & 3) * 16;

  f32x4 acc[4][6];
#pragma unroll
  for (int i = 0; i < 4; ++i)
#pragma unroll
    for (int j = 0; j < 6; ++j) acc[i][j] = (f32x4){0.f, 0.f, 0.f, 0.f};

  for (int kt = 0; kt < 64; ++kt) {
    __syncthreads();  // previous tile's LDS reads complete before overwrite
    // --- A: fp32 x -> registers ---
    const float4* xs =
        (const float4*)(x + (size_t)(m0 + arow) * 4096 + kt * 64 + kseg);
    float4 f0 = xs[0], f1 = xs[1], f2 = xs[2], f3 = xs[3];
    // --- B: bf16 Wt -> LDS async ---
    {
      const bf16_t* wb = wt + kt * 64;
#pragma unroll
      for (int r = 0; r < 12; ++r) {  // 3072 chunks of 16B
        int cbase = r * 256 + w * 64;
        int cid = cbase + lane;
        int n = cid >> 3, cc = cid & 7;
        async_cp16(wb + (size_t)n * 4096 + cc * 8, sB + (size_t)cbase * 8);
      }
    }
    // --- A: cvt + ds_write (2x 16B) ---
    {
      f32x8 flo = {f0.x, f0.y, f0.z, f0.w, f1.x, f1.y, f1.z, f1.w};
      f32x8 fhi = {f2.x, f2.y, f2.z, f2.w, f3.x, f3.y, f3.z, f3.w};
      *(bf16x8*)(sA + arow * 64 + kseg) = __builtin_convertvector(flo, bf16x8);
      *(bf16x8*)(sA + arow * 64 + kseg + 8) = __builtin_convertvector(fhi, bf16x8);
    }
    __syncthreads();  // staging drained (vmcnt for B, lgkm for A)
#pragma unroll
    for (int ks = 0; ks < 2; ++ks) {
      bf16x8 af[4], bfr[6];
      const int cc = ks * 4 + quad;
#pragma unroll
      for (int mt = 0; mt < 4; ++mt)
        af[mt] = *(const bf16x8*)(sA + (mt * 16 + lq) * 64 + cc * 8);
#pragma unroll
      for (int nt = 0; nt < 6; ++nt)
        bfr[nt] = *(const bf16x8*)(sB + (w * 96 + nt * 16 + lq) * 64 + cc * 8);
#pragma unroll
      for (int mt = 0; mt < 4; ++mt)
#pragma unroll
        for (int nt = 0; nt < 6; ++nt) acc[mt][nt] = MFMA16(af[mt], bfr[nt], acc[mt][nt]);
    }
  }
  // epilogue: C/D layout col(n)=lane&15, row(m)=quad*4+reg
#pragma unroll
  for (int mt = 0; mt < 4; ++mt) {
#pragma unroll
    for (int nt = 0; nt < 6; ++nt) {
      int n = w * 96 + nt * 16 + lq;
      bf16_t* dst;
      int nn;
      if (n < 128) { dst = q; nn = n; }
      else if (n < 256) { dst = k; nn = n - 128; }
      else { dst = v; nn = n - 256; }
#pragma unroll
      for (int r = 0; r < 4; ++r) {
        int m = m0 + mt * 16 + quad * 4 + r;
        dst[(size_t)m * 128 + nn] = (bf16_t)acc[mt][nt][r];
      }
    }
  }
}

// ---------------- flash attention (single-buffered, fully barriered) ----------
// Grid 256: b = blockIdx.x & 3, qt = blockIdx.x >> 2. Block: 64 Q rows;
// wave w owns rows [w*16, w*16+16). 64-key tiles. Output fp32.
__launch_bounds__(256, 1)
__global__ void flash(const bf16_t* __restrict__ q, const bf16_t* __restrict__ kk,
                      const bf16_t* __restrict__ vt, float* __restrict__ out) {
  __shared__ __align__(16) bf16_t sK[64 * 128];   // [key][h], 16x16B chunks/row
  __shared__ __align__(16) bf16_t sV[128 * 64];   // [h][key], 8x16B chunks/row
  __shared__ __align__(16) bf16_t sP[64 * 72];    // [qrow][key], row stride 72
  const int tid = threadIdx.x;
  const int w = tid >> 6, lane = tid & 63, lq = lane & 15, quad = lane >> 4;
  const int b = blockIdx.x & 3;
  const int qt = blockIdx.x >> 2;
  const int qrow0 = qt * 64;

  bf16x8 qf[4];  // Q A-fragments, full head dim, registers
  {
    const bf16_t* qp = q + ((size_t)b * 4096 + qrow0 + w * 16 + lq) * 128 + quad * 8;
#pragma unroll
    for (int ks = 0; ks < 4; ++ks) qf[ks] = *(const bf16x8*)(qp + ks * 32);
  }

  f32x4 accO[8];
#pragma unroll
  for (int i = 0; i < 8; ++i) accO[i] = (f32x4){0.f, 0.f, 0.f, 0.f};
  float mrow[4] = {-1e30f, -1e30f, -1e30f, -1e30f};
  float lrow[4] = {0.f, 0.f, 0.f, 0.f};

  const bf16_t* kbase = kk + (size_t)b * 4096 * 128;
  const bf16_t* vbase = vt + (size_t)b * 128 * 4096;
  const float SCL = 0.08838834764831845f * 1.4426950408889634f;  // 1/sqrt(128)*log2(e)

  for (int it = 0; it < 64; ++it) {
    __syncthreads();  // prior iteration's sK/sV/sP reads complete
    {
      const bf16_t* ksrc = kbase + (size_t)it * 64 * 128;
#pragma unroll
      for (int r = 0; r < 4; ++r) {  // K tile: 1024 chunks
        int cbase = r * 256 + w * 64;
        int cid = cbase + lane;
        int row = cid >> 4, cc = cid & 15;
        async_cp16(ksrc + row * 128 + cc * 8, sK + (size_t)cbase * 8);
      }
      const bf16_t* vsrc = vbase + it * 64;
#pragma unroll
      for (int r = 0; r < 4; ++r) {  // Vt tile: 1024 chunks
        int cbase = r * 256 + w * 64;
        int cid = cbase + lane;
        int h = cid >> 3, cc = cid & 7;
        async_cp16(vsrc + (size_t)h * 4096 + cc * 8, sV + (size_t)cbase * 8);
      }
    }
    __syncthreads();  // staging drained

    // --- S = Q K^T for this wave's 16 rows x 64 keys ---
    f32x4 accS[4];
#pragma unroll
    for (int nt = 0; nt < 4; ++nt) accS[nt] = (f32x4){0.f, 0.f, 0.f, 0.f};
#pragma unroll
    for (int ks = 0; ks < 4; ++ks) {
      const int cc = ks * 4 + quad;
#pragma unroll
      for (int nt = 0; nt < 4; ++nt) {
        bf16x8 kf = *(const bf16x8*)(sK + (nt * 16 + lq) * 128 + cc * 8);
        accS[nt] = MFMA16(qf[ks], kf, accS[nt]);
      }
    }

    // --- online softmax: rows = quad*4+r (S C-layout), cols = lane&15 ---
#pragma unroll
    for (int nt = 0; nt < 4; ++nt) accS[nt] *= SCL;
    float mx[4];
#pragma unroll
    for (int r = 0; r < 4; ++r) {
      float t0 = fmaxf(fmaxf(accS[0][r], accS[1][r]), fmaxf(accS[2][r], accS[3][r]));
#pragma unroll
      for (int msk = 1; msk < 16; msk <<= 1) t0 = fmaxf(t0, __shfl_xor(t0, msk));
      mx[r] = t0;
    }
    float al[4];
#pragma unroll
    for (int r = 0; r < 4; ++r) {
      float mn = fmaxf(mrow[r], mx[r]);
      al[r] = exp2f(mrow[r] - mn);
      mrow[r] = mn;
    }
    float ps[4] = {0.f, 0.f, 0.f, 0.f};
#pragma unroll
    for (int nt = 0; nt < 4; ++nt)
#pragma unroll
      for (int r = 0; r < 4; ++r) {
        float p = exp2f(accS[nt][r] - mrow[r]);
        accS[nt][r] = p;
        ps[r] += p;
      }
#pragma unroll
    for (int r = 0; r < 4; ++r) {
      float s = ps[r];
#pragma unroll
      for (int msk = 1; msk < 16; msk <<= 1) s += __shfl_xor(s, msk);
      lrow[r] = lrow[r] * al[r] + s;
    }
#pragma unroll
    for (int ot = 0; ot < 8; ++ot) {
      accO[ot][0] *= al[0]; accO[ot][1] *= al[1];
      accO[ot][2] *= al[2]; accO[ot][3] *= al[3];
    }

    // --- write P (bf16) to sP[qrow][key] ---
#pragma unroll
    for (int nt = 0; nt < 4; ++nt) {
      int key = nt * 16 + lq;
#pragma unroll
      for (int r = 0; r < 4; ++r) {
        int prow = w * 16 + quad * 4 + r;
        sP[prow * 72 + key] = (bf16_t)accS[nt][r];
      }
    }
    __syncthreads();  // P visible

    // --- O += P V ---
#pragma unroll
    for (int ks2 = 0; ks2 < 2; ++ks2) {
      const int cc = ks2 * 4 + quad;
      bf16x8 pf = *(const bf16x8*)(sP + (w * 16 + lq) * 72 + cc * 8);
#pragma unroll
      for (int ot = 0; ot < 8; ++ot) {
        bf16x8 vf = *(const bf16x8*)(sV + (ot * 16 + lq) * 64 + cc * 8);
        accO[ot] = MFMA16(pf, vf, accO[ot]);
      }
    }
  }

  float inv[4];
#pragma unroll
  for (int r = 0; r < 4; ++r) inv[r] = 1.0f / lrow[r];
  float* ob = out + ((size_t)b * 4096 + qrow0 + w * 16) * 128;
#pragma unroll
  for (int ot = 0; ot < 8; ++ot)
#pragma unroll
    for (int r = 0; r < 4; ++r)
      ob[(size_t)(quad * 4 + r) * 128 + ot * 16 + lq] = accO[ot][r] * inv[r];
}

extern "C" void kernel_launch(void* const* d_in, const int* in_sizes, int n_in,
                              void* d_out, int out_size, void* d_ws, size_t ws_size,
                              hipStream_t stream) {
  (void)in_sizes; (void)n_in; (void)out_size; (void)ws_size;
  const float* x  = (const float*)d_in[0];
  const float* wq = (const float*)d_in[1];
  const float* wk = (const float*)d_in[2];
  const float* wv = (const float*)d_in[3];

  bf16_t* wt  = (bf16_t*)d_ws;                  // 384*4096
  bf16_t* qb  = wt + (size_t)384 * 4096;        // 16384*128
  bf16_t* kb  = qb + (size_t)16384 * 128;
  bf16_t* vb  = kb + (size_t)16384 * 128;
  bf16_t* vtb = vb + (size_t)16384 * 128;       // (B,128,T)
  float*  ob  = (float*)d_out;

  dim3 tb(32, 8, 1);
  tr_w<<<dim3(4, 128, 3), tb, 0, stream>>>(wq, wk, wv, wt);
  qkv_proj<<<dim3(256), dim3(256), 0, stream>>>(x, wt, qb, kb, vb);
  tr_v<<<dim3(4, 128, 4), tb, 0, stream>>>(vb, vtb);
  flash<<<dim3(256), dim3(256), 0, stream>>>(qb, kb, vtb, ob);
}

// Round 4
// 538.202 us; speedup vs baseline: 1.2191x; 1.2191x over previous
//
#include <hip/hip_runtime.h>

// SelfAttention: B=4, T=4096, D=4096, H=128. fp32 in/out, bf16 MFMA compute.
// R4: XOR-swizzled LDS (kills 16-way bank conflicts), flash key-split x4
// (grid 1024, 3 blocks/CU) + merge kernel, qkv M=32 grid 512.

typedef __bf16 bf16_t;
typedef bf16_t bf16x8 __attribute__((ext_vector_type(8)));
typedef float f32x4 __attribute__((ext_vector_type(4)));
typedef float f32x8 __attribute__((ext_vector_type(8)));

#define MFMA16(A, B, C) __builtin_amdgcn_mfma_f32_16x16x32_bf16((A), (B), (C), 0, 0, 0)

__device__ __forceinline__ void async_cp16(const bf16_t* g, bf16_t* lds) {
  // 16B direct global->LDS. LDS dest = wave-uniform base + lane*16.
  __builtin_amdgcn_global_load_lds(
      (__attribute__((address_space(1))) unsigned int*)g,
      (__attribute__((address_space(3))) unsigned int*)lds, 16, 0, 0);
}

// ---------------- transpose W: 3x fp32 (4096,128) -> bf16 Wt (384,4096) -------
__global__ void tr_w(const float* __restrict__ w0, const float* __restrict__ w1,
                     const float* __restrict__ w2, bf16_t* __restrict__ wt) {
  __shared__ float tile[32][33];
  const int z = blockIdx.z;
  const float* src = (z == 0) ? w0 : (z == 1) ? w1 : w2;
  bf16_t* dst = wt + (size_t)z * 128 * 4096;
  const int c0 = blockIdx.x * 32;
  const int r0 = blockIdx.y * 32;
  const int tx = threadIdx.x, ty = threadIdx.y;
#pragma unroll
  for (int j = 0; j < 4; ++j)
    tile[ty + 8 * j][tx] = src[(size_t)(r0 + ty + 8 * j) * 128 + c0 + tx];
  __syncthreads();
#pragma unroll
  for (int j = 0; j < 4; ++j)
    dst[(size_t)(c0 + ty + 8 * j) * 4096 + r0 + tx] = (bf16_t)tile[tx][ty + 8 * j];
}

// ---------------- transpose V: bf16 (B,4096,128) -> bf16 Vt (B,128,4096) ------
__global__ void tr_v(const bf16_t* __restrict__ v, bf16_t* __restrict__ vt) {
  __shared__ bf16_t tile[32][33];
  const int b = blockIdx.z;
  const bf16_t* src = v + (size_t)b * 4096 * 128;
  bf16_t* dst = vt + (size_t)b * 128 * 4096;
  const int c0 = blockIdx.x * 32;
  const int r0 = blockIdx.y * 32;
  const int tx = threadIdx.x, ty = threadIdx.y;
#pragma unroll
  for (int j = 0; j < 4; ++j)
    tile[ty + 8 * j][tx] = src[(size_t)(r0 + ty + 8 * j) * 128 + c0 + tx];
  __syncthreads();
#pragma unroll
  for (int j = 0; j < 4; ++j)
    dst[(size_t)(c0 + ty + 8 * j) * 4096 + r0 + tx] = tile[tx][ty + 8 * j];
}

// ---------------- fused QKV projection: fp32 (16384,4096) @ Wt -> 3x bf16 ------
// M=32, N=384, BK=64; grid 512 (2 blocks/CU). Wave w -> cols [w*96, w*96+96).
// LDS physical chunk = logical chunk ^ (row & 7)  => fragment reads 2-way (free).
__launch_bounds__(256, 1)
__global__ void qkv_proj(const float* __restrict__ x, const bf16_t* __restrict__ wt,
                         bf16_t* __restrict__ q, bf16_t* __restrict__ k,
                         bf16_t* __restrict__ v) {
  __shared__ __align__(16) bf16_t sA[32 * 64];    // [m][k], 8x16B chunks/row, swizzled
  __shared__ __align__(16) bf16_t sB[384 * 64];   // [n][k], 8x16B chunks/row, swizzled
  const int tid = threadIdx.x;
  const int w = tid >> 6, lane = tid & 63, lq = lane & 15, quad = lane >> 4;
  const int m0 = blockIdx.x * 32;
  // A staging: thread -> row 0..31, physical chunk 0..7; fetch logical chunk pc^(row&7)
  const int arow = tid >> 3, apc = tid & 7;
  const int alc = apc ^ (arow & 7);

  f32x4 acc[2][6];
#pragma unroll
  for (int i = 0; i < 2; ++i)
#pragma unroll
    for (int j = 0; j < 6; ++j) acc[i][j] = (f32x4){0.f, 0.f, 0.f, 0.f};

  for (int kt = 0; kt < 64; ++kt) {
    __syncthreads();  // previous tile's LDS reads complete before overwrite
    // --- A: fp32 x -> registers (8 floats = one 16B bf16 chunk) ---
    const float4* xs = (const float4*)(x + (size_t)(m0 + arow) * 4096 + kt * 64 + alc * 8);
    float4 f0 = xs[0], f1 = xs[1];
    // --- B: bf16 Wt -> LDS async, swizzled source chunk ---
    {
      const bf16_t* wb = wt + kt * 64;
#pragma unroll
      for (int r = 0; r < 12; ++r) {  // 3072 chunks of 16B
        int cid = r * 256 + tid;
        int n = cid >> 3, pc = cid & 7;
        int lc = pc ^ (n & 7);
        async_cp16(wb + (size_t)n * 4096 + lc * 8, sB + (size_t)cid * 8);
      }
    }
    // --- A: cvt + one swizzled 16B ds_write ---
    {
      f32x8 ff = {f0.x, f0.y, f0.z, f0.w, f1.x, f1.y, f1.z, f1.w};
      *(bf16x8*)(sA + arow * 64 + apc * 8) = __builtin_convertvector(ff, bf16x8);
    }
    __syncthreads();  // staging drained
#pragma unroll
    for (int ks = 0; ks < 2; ++ks) {
      bf16x8 af[2], bfr[6];
      const int cc = ks * 4 + quad;
#pragma unroll
      for (int mt = 0; mt < 2; ++mt) {
        int row = mt * 16 + lq;
        af[mt] = *(const bf16x8*)(sA + row * 64 + ((cc ^ (row & 7)) << 3));
      }
#pragma unroll
      for (int nt = 0; nt < 6; ++nt) {
        int n = w * 96 + nt * 16 + lq;
        bfr[nt] = *(const bf16x8*)(sB + n * 64 + ((cc ^ (n & 7)) << 3));
      }
#pragma unroll
      for (int mt = 0; mt < 2; ++mt)
#pragma unroll
        for (int nt = 0; nt < 6; ++nt) acc[mt][nt] = MFMA16(af[mt], bfr[nt], acc[mt][nt]);
    }
  }
  // epilogue: C/D layout col(n)=lane&15, row(m)=quad*4+reg
#pragma unroll
  for (int mt = 0; mt < 2; ++mt) {
#pragma unroll
    for (int nt = 0; nt < 6; ++nt) {
      int n = w * 96 + nt * 16 + lq;
      bf16_t* dst;
      int nn;
      if (n < 128) { dst = q; nn = n; }
      else if (n < 256) { dst = k; nn = n - 128; }
      else { dst = v; nn = n - 256; }
#pragma unroll
      for (int r = 0; r < 4; ++r) {
        int m = m0 + mt * 16 + quad * 4 + r;
        dst[(size_t)m * 128 + nn] = (bf16_t)acc[mt][nt][r];
      }
    }
  }
}

// ---------------- flash attention, key-split x4 -------------------------------
// Grid 1024: b = x&3, qt = (x>>2)&63, split sp = x>>8. Block: 64 Q rows, 256 thr;
// wave w owns rows [w*16, w*16+16). Each block does 16 key-tiles of 64 keys.
// Writes fp32 partial (O_acc, m, l); merge kernel combines the 4 splits.
__launch_bounds__(256, 1)
__global__ void flash(const bf16_t* __restrict__ q, const bf16_t* __restrict__ kk,
                      const bf16_t* __restrict__ vt, float* __restrict__ opart,
                      float* __restrict__ mlm, float* __restrict__ mll) {
  __shared__ __align__(16) bf16_t sK[64 * 128];   // [key][h], 16 chunks/row, swizzled &15
  __shared__ __align__(16) bf16_t sV[128 * 64];   // [h][key], 8 chunks/row, swizzled &7
  __shared__ __align__(16) bf16_t sP[64 * 72];    // [qrow][key], stride 72 (self-de-conflicting)
  const int tid = threadIdx.x;
  const int w = tid >> 6, lane = tid & 63, lq = lane & 15, quad = lane >> 4;
  const int b = blockIdx.x & 3;
  const int qt = (blockIdx.x >> 2) & 63;
  const int sp = blockIdx.x >> 8;
  const int qrow0 = qt * 64;

  bf16x8 qf[4];  // Q A-fragments, full head dim
  {
    const bf16_t* qp = q + ((size_t)b * 4096 + qrow0 + w * 16 + lq) * 128 + quad * 8;
#pragma unroll
    for (int ks = 0; ks < 4; ++ks) qf[ks] = *(const bf16x8*)(qp + ks * 32);
  }

  f32x4 accO[8];
#pragma unroll
  for (int i = 0; i < 8; ++i) accO[i] = (f32x4){0.f, 0.f, 0.f, 0.f};
  float mrow[4] = {-1e30f, -1e30f, -1e30f, -1e30f};
  float lrow[4] = {0.f, 0.f, 0.f, 0.f};

  const bf16_t* kbase = kk + (size_t)b * 4096 * 128;
  const bf16_t* vbase = vt + (size_t)b * 128 * 4096;
  const float SCL = 0.08838834764831845f * 1.4426950408889634f;  // 1/sqrt(128)*log2(e)

  for (int it = sp * 16; it < sp * 16 + 16; ++it) {
    __syncthreads();  // prior iteration's sK/sV/sP reads complete
    {
      const bf16_t* ksrc = kbase + (size_t)it * 64 * 128;
#pragma unroll
      for (int r = 0; r < 4; ++r) {  // K tile: 1024 chunks
        int cid = r * 256 + tid;
        int row = cid >> 4, pc = cid & 15;
        int lc = pc ^ (row & 15);
        async_cp16(ksrc + row * 128 + lc * 8, sK + (size_t)cid * 8);
      }
      const bf16_t* vsrc = vbase + it * 64;
#pragma unroll
      for (int r = 0; r < 4; ++r) {  // Vt tile: 1024 chunks
        int cid = r * 256 + tid;
        int h = cid >> 3, pc = cid & 7;
        int lc = pc ^ (h & 7);
        async_cp16(vsrc + (size_t)h * 4096 + lc * 8, sV + (size_t)cid * 8);
      }
    }
    __syncthreads();  // staging drained

    // --- S = Q K^T: this wave's 16 rows x 64 keys ---
    f32x4 accS[4];
#pragma unroll
    for (int nt = 0; nt < 4; ++nt) accS[nt] = (f32x4){0.f, 0.f, 0.f, 0.f};
#pragma unroll
    for (int ks = 0; ks < 4; ++ks) {
      const int cc = ks * 4 + quad;
#pragma unroll
      for (int nt = 0; nt < 4; ++nt) {
        int row = nt * 16 + lq;
        bf16x8 kf = *(const bf16x8*)(sK + row * 128 + ((cc ^ (row & 15)) << 3));
        accS[nt] = MFMA16(qf[ks], kf, accS[nt]);
      }
    }

    // --- online softmax: rows = quad*4+r, cols = lane&15 ---
#pragma unroll
    for (int nt = 0; nt < 4; ++nt) accS[nt] *= SCL;
    float mx[4];
#pragma unroll
    for (int r = 0; r < 4; ++r) {
      float t0 = fmaxf(fmaxf(accS[0][r], accS[1][r]), fmaxf(accS[2][r], accS[3][r]));
#pragma unroll
      for (int msk = 1; msk < 16; msk <<= 1) t0 = fmaxf(t0, __shfl_xor(t0, msk));
      mx[r] = t0;
    }
    float al[4];
#pragma unroll
    for (int r = 0; r < 4; ++r) {
      float mn = fmaxf(mrow[r], mx[r]);
      al[r] = exp2f(mrow[r] - mn);
      mrow[r] = mn;
    }
    float ps[4] = {0.f, 0.f, 0.f, 0.f};
#pragma unroll
    for (int nt = 0; nt < 4; ++nt)
#pragma unroll
      for (int r = 0; r < 4; ++r) {
        float p = exp2f(accS[nt][r] - mrow[r]);
        accS[nt][r] = p;
        ps[r] += p;
      }
#pragma unroll
    for (int r = 0; r < 4; ++r) {
      float s = ps[r];
#pragma unroll
      for (int msk = 1; msk < 16; msk <<= 1) s += __shfl_xor(s, msk);
      lrow[r] = lrow[r] * al[r] + s;
    }
#pragma unroll
    for (int ot = 0; ot < 8; ++ot) {
      accO[ot][0] *= al[0]; accO[ot][1] *= al[1];
      accO[ot][2] *= al[2]; accO[ot][3] *= al[3];
    }

    // --- write P (bf16) to sP[qrow][key] ---
#pragma unroll
    for (int nt = 0; nt < 4; ++nt) {
      int key = nt * 16 + lq;
#pragma unroll
      for (int r = 0; r < 4; ++r) {
        int prow = w * 16 + quad * 4 + r;
        sP[prow * 72 + key] = (bf16_t)accS[nt][r];
      }
    }
    __syncthreads();  // P visible

    // --- O += P V ---
#pragma unroll
    for (int ks2 = 0; ks2 < 2; ++ks2) {
      const int cc = ks2 * 4 + quad;
      bf16x8 pf = *(const bf16x8*)(sP + (w * 16 + lq) * 72 + cc * 8);
#pragma unroll
      for (int ot = 0; ot < 8; ++ot) {
        int h = ot * 16 + lq;
        bf16x8 vf = *(const bf16x8*)(sV + h * 64 + ((cc ^ (h & 7)) << 3));
        accO[ot] = MFMA16(pf, vf, accO[ot]);
      }
    }
  }

  // --- store fp32 partials (unnormalized) + m,l ---
  float* op = opart + ((size_t)(sp * 4 + b) * 4096 + qrow0 + w * 16) * 128;
#pragma unroll
  for (int ot = 0; ot < 8; ++ot)
#pragma unroll
    for (int r = 0; r < 4; ++r)
      op[(size_t)(quad * 4 + r) * 128 + ot * 16 + lq] = accO[ot][r];
  if (lq == 0) {
#pragma unroll
    for (int r = 0; r < 4; ++r) {
      size_t idx = (size_t)(sp * 4 + b) * 4096 + qrow0 + w * 16 + quad * 4 + r;
      mlm[idx] = mrow[r];
      mll[idx] = lrow[r];
    }
  }
}

// ---------------- merge the 4 key-splits --------------------------------------
__global__ void merge(const float* __restrict__ opart, const float* __restrict__ mlm,
                      const float* __restrict__ mll, float* __restrict__ out) {
  const int idx = blockIdx.x * 256 + threadIdx.x;  // 2M elements
  const int h = idx & 127;
  const int row = idx >> 7;  // b*4096 + t
  float m[4], l[4];
#pragma unroll
  for (int s = 0; s < 4; ++s) {
    m[s] = mlm[s * 16384 + row];
    l[s] = mll[s * 16384 + row];
  }
  float M = fmaxf(fmaxf(m[0], m[1]), fmaxf(m[2], m[3]));
  float L = 0.f, acc = 0.f;
#pragma unroll
  for (int s = 0; s < 4; ++s) {
    float wgt = exp2f(m[s] - M);
    L += wgt * l[s];
    acc += wgt * opart[((size_t)s * 16384 + row) * 128 + h];
  }
  out[idx] = acc / L;
}

extern "C" void kernel_launch(void* const* d_in, const int* in_sizes, int n_in,
                              void* d_out, int out_size, void* d_ws, size_t ws_size,
                              hipStream_t stream) {
  (void)in_sizes; (void)n_in; (void)out_size; (void)ws_size;
  const float* x  = (const float*)d_in[0];
  const float* wq = (const float*)d_in[1];
  const float* wk = (const float*)d_in[2];
  const float* wv = (const float*)d_in[3];

  char* ws = (char*)d_ws;
  bf16_t* wt  = (bf16_t*)ws;                         ws += (size_t)384 * 4096 * 2;
  bf16_t* qb  = (bf16_t*)ws;                         ws += (size_t)16384 * 128 * 2;
  bf16_t* kb  = (bf16_t*)ws;                         ws += (size_t)16384 * 128 * 2;
  bf16_t* vb  = (bf16_t*)ws;                         ws += (size_t)16384 * 128 * 2;
  bf16_t* vtb = (bf16_t*)ws;                         ws += (size_t)16384 * 128 * 2;
  float*  opart = (float*)ws;                        ws += (size_t)4 * 16384 * 128 * 4;
  float*  mlm = (float*)ws;                          ws += (size_t)4 * 16384 * 4;
  float*  mll = (float*)ws;
  float*  ob  = (float*)d_out;

  dim3 tb(32, 8, 1);
  tr_w<<<dim3(4, 128, 3), tb, 0, stream>>>(wq, wk, wv, wt);
  qkv_proj<<<dim3(512), dim3(256), 0, stream>>>(x, wt, qb, kb, vb);
  tr_v<<<dim3(4, 128, 4), tb, 0, stream>>>(vb, vtb);
  flash<<<dim3(1024), dim3(256), 0, stream>>>(qb, kb, vtb, opart, mlm, mll);
  merge<<<dim3(8192), dim3(256), 0, stream>>>(opart, mlm, mll, ob);
}